// Round 1
// baseline (354.375 us; speedup 1.0000x reference)
//
#include <hip/hip_runtime.h>

typedef _Float16 h8 __attribute__((ext_vector_type(8)));
typedef _Float16 h4 __attribute__((ext_vector_type(4)));
typedef float f4 __attribute__((ext_vector_type(4)));

#define NHEADS 6
#define LOGMAX 4.6051701859880914f   // ln(100)

// kept position j (0..31) -> row index in window (0..63); kept iff (r+c) even
__device__ __forceinline__ int S_of(int j) { return ((j >> 2) << 3) + ((j & 3) << 1) + ((j >> 2) & 1); }
// complement (masked) position
__device__ __forceinline__ int SC_of(int j) { return ((j >> 2) << 3) + ((j & 3) << 1) + (1 - ((j >> 2) & 1)); }

// ---------------------------------------------------------------------------
// Pack kernel: weights -> fp16 in MFMA B-fragment order; bias table pre-gather.
// qkv packed: [h][nt 0..5][ks 0..5][lane 0..63][8]
//   nt: 0,1 = q cols 0:16,16:32 ; 2,3 = k ; 4,5 = v
//   element = qkv_w[o][k], o = (nt>>1)*192 + h*32 + (nt&1)*16 + (lane&15),
//   k = ks*32 + (lane>>4)*8 + j
// proj packed: [nt 0..11][ks 0..5][lane][8] = proj_w[nt*16+(lane&15)][ks*32+(lane>>4)*8+j]
// biask: [h][32][32] = rel_bias_table[rel_pos_index[S(row)][S(col)]][h]
// ---------------------------------------------------------------------------
__global__ void pack_kernel(const float* __restrict__ qkv_w,
                            const float* __restrict__ proj_w,
                            const float* __restrict__ rel_bias_table,
                            const int* __restrict__ rel_pos_index,
                            _Float16* __restrict__ qkvp,
                            _Float16* __restrict__ projp,
                            float* __restrict__ biask) {
    int tid = blockIdx.x * 256 + threadIdx.x;
    const int NQ = 6 * 6 * 6 * 64;        // 13824
    const int NP = 12 * 6 * 64;           // 4608
    if (tid < NQ) {
        int l = tid & 63;
        int rest = tid >> 6;
        int ks = rest % 6;
        int nt = (rest / 6) % 6;
        int h = rest / 36;
        int o = (nt >> 1) * 192 + h * 32 + (nt & 1) * 16 + (l & 15);
        int k0 = ks * 32 + (l >> 4) * 8;
        const float* src = qkv_w + o * 192 + k0;
        _Float16* dst = qkvp + tid * 8;
#pragma unroll
        for (int j = 0; j < 8; ++j) dst[j] = (_Float16)src[j];
    } else if (tid < NQ + NP) {
        int t = tid - NQ;
        int l = t & 63;
        int rest = t >> 6;
        int ks = rest % 6;
        int nt = rest / 6;
        int o = nt * 16 + (l & 15);
        int k0 = ks * 32 + (l >> 4) * 8;
        const float* src = proj_w + o * 192 + k0;
        _Float16* dst = projp + t * 8;
#pragma unroll
        for (int j = 0; j < 8; ++j) dst[j] = (_Float16)src[j];
    } else if (tid < NQ + NP + 6 * 32 * 32) {
        int t = tid - (NQ + NP);
        int h = t >> 10;
        int jr = (t >> 5) & 31;
        int ic = t & 31;
        int rp = rel_pos_index[S_of(jr) * 64 + S_of(ic)];
        biask[t] = rel_bias_table[rp * NHEADS + h];
    }
}

// ---------------------------------------------------------------------------
// Main fused kernel: 1 block = 2 windows, 256 threads = 4 waves.
// ---------------------------------------------------------------------------
#define XS_S 200   // Xs / outS row stride (f16): 400B, 16B aligned, 2-way banks
#define QN_S 40    // qn / kn / pl row stride: 80B
#define VT_S 72    // vT row stride: 144B

__global__ __launch_bounds__(256, 2) void cwa_kernel(
    const float* __restrict__ x,
    const _Float16* __restrict__ qkvp,
    const _Float16* __restrict__ projp,
    const float* __restrict__ biask,
    const float* __restrict__ qkv_b,
    const float* __restrict__ proj_b,
    const float* __restrict__ logit_scale,
    float* __restrict__ out) {
    __shared__ __align__(16) _Float16 Xs[64 * XS_S];
    __shared__ __align__(16) _Float16 qn[64 * QN_S];
    __shared__ __align__(16) _Float16 kn[64 * QN_S];
    __shared__ __align__(16) _Float16 vT[32 * VT_S];
    __shared__ __align__(16) _Float16 pl[64 * QN_S];
    __shared__ __align__(16) _Float16 outS[64 * XS_S];

    const int tid = threadIdx.x;
    const int lane = tid & 63;
    const int wave = tid >> 6;
    const int cl = lane & 15;
    const int g = lane >> 4;
    const int w0 = blockIdx.x * 2;
    const int wm = wave >> 1;  // phase A: m-half; phase B: window
    const int wn = wave & 1;   // phase A: n-half; phase B: row-half

    // ---- masked rows: output = proj_b ----
    {
        int rowi = tid >> 2;   // 0..63  (2 windows x 32 masked rows)
        int sub = tid & 3;
        long base = ((long)(w0 + (rowi >> 5)) * 64 + SC_of(rowi & 31)) * 192;
#pragma unroll
        for (int i = 0; i < 12; ++i) {
            int c4 = i * 4 + sub;
            *(f4*)(out + base + c4 * 4) = *(const f4*)(proj_b + c4 * 4);
        }
    }

    // ---- load kept rows of x -> fp16 LDS ----
    {
        int rowi = tid >> 2;
        int sub = tid & 3;
        long base = ((long)(w0 + (rowi >> 5)) * 64 + S_of(rowi & 31)) * 192;
#pragma unroll
        for (int i = 0; i < 12; ++i) {
            int c4 = i * 4 + sub;
            f4 v = *(const f4*)(x + base + c4 * 4);
            h4 hv;
            hv[0] = (_Float16)v[0]; hv[1] = (_Float16)v[1];
            hv[2] = (_Float16)v[2]; hv[3] = (_Float16)v[3];
            *(h4*)(&Xs[rowi * XS_S + c4 * 4]) = hv;
        }
    }
    __syncthreads();

    for (int h = 0; h < NHEADS; ++h) {
        // ================= Phase A: qkv GEMM for head h =================
        f4 acc0[3]; f4 acc1[3];
#pragma unroll
        for (int ni = 0; ni < 3; ++ni) { acc0[ni] = 0.0f; acc1[ni] = 0.0f; }
#pragma unroll
        for (int ks = 0; ks < 6; ++ks) {
            h8 a0 = *(const h8*)(&Xs[(wm * 32 + cl) * XS_S + ks * 32 + g * 8]);
            h8 a1 = *(const h8*)(&Xs[(wm * 32 + 16 + cl) * XS_S + ks * 32 + g * 8]);
#pragma unroll
            for (int ni = 0; ni < 3; ++ni) {
                int nt = wn ? (ni == 2 ? 5 : ni + 2) : (ni == 2 ? 4 : ni);
                h8 b = *(const h8*)(qkvp + ((((h * 6 + nt) * 6 + ks) * 64 + lane) << 3));
                acc0[ni] = __builtin_amdgcn_mfma_f32_16x16x32_f16(a0, b, acc0[ni], 0, 0, 0);
                acc1[ni] = __builtin_amdgcn_mfma_f32_16x16x32_f16(a1, b, acc1[ni], 0, 0, 0);
            }
        }
        // bias add + L2-norm (q,k) + store; v stored transposed
        float b0, b1, b2;
        if (wn == 0) {
            b0 = qkv_b[h * 32 + cl]; b1 = qkv_b[h * 32 + 16 + cl];
            b2 = qkv_b[384 + h * 32 + cl];
        } else {
            b0 = qkv_b[192 + h * 32 + cl]; b1 = qkv_b[192 + h * 32 + 16 + cl];
            b2 = qkv_b[384 + h * 32 + 16 + cl];
        }
        _Float16* dstQK = (wn == 0) ? qn : kn;
#pragma unroll
        for (int m = 0; m < 2; ++m) {
            const f4* am = m ? acc1 : acc0;
            int rb = wm * 32 + m * 16 + g * 4;
#pragma unroll
            for (int r = 0; r < 4; ++r) {
                float t0 = am[0][r] + b0;
                float t1 = am[1][r] + b1;
                float ss = t0 * t0 + t1 * t1;
#pragma unroll
                for (int msk = 1; msk < 16; msk <<= 1) ss += __shfl_xor(ss, msk, 16);
                float rs = 1.0f / fmaxf(sqrtf(ss), 1e-12f);
                dstQK[(rb + r) * QN_S + cl] = (_Float16)(t0 * rs);
                dstQK[(rb + r) * QN_S + 16 + cl] = (_Float16)(t1 * rs);
                float tv = am[2][r] + b2;
                vT[(wn * 16 + cl) * VT_S + rb + r] = (_Float16)tv;
            }
        }
        __syncthreads();

        // ================= Phase B: attention (window wm, rows half wn) =====
        {
            int qb = wm * 32 + wn * 16;
            h8 aq = *(const h8*)(&qn[(qb + cl) * QN_S + g * 8]);
            f4 sN[2];
            sN[0] = 0.0f; sN[1] = 0.0f;
#pragma unroll
            for (int nt = 0; nt < 2; ++nt) {
                h8 bk = *(const h8*)(&kn[(wm * 32 + nt * 16 + cl) * QN_S + g * 8]);
                sN[nt] = __builtin_amdgcn_mfma_f32_16x16x32_f16(aq, bk, sN[nt], 0, 0, 0);
            }
            float scale = __expf(fminf(logit_scale[h], LOGMAX));
            float lg[2][4];
#pragma unroll
            for (int nt = 0; nt < 2; ++nt)
#pragma unroll
                for (int r = 0; r < 4; ++r)
                    lg[nt][r] = sN[nt][r] * scale +
                                biask[h * 1024 + (wn * 16 + g * 4 + r) * 32 + nt * 16 + cl];
            float po[2][4];
#pragma unroll
            for (int r = 0; r < 4; ++r) {
                float mx = fmaxf(lg[0][r], lg[1][r]);
#pragma unroll
                for (int msk = 1; msk < 16; msk <<= 1) mx = fmaxf(mx, __shfl_xor(mx, msk, 16));
                float e0 = __expf(lg[0][r] - mx);
                float e1 = __expf(lg[1][r] - mx);
                float sm = e0 + e1;
#pragma unroll
                for (int msk = 1; msk < 16; msk <<= 1) sm += __shfl_xor(sm, msk, 16);
                float inv = 1.0f / sm;
                po[0][r] = e0 * inv; po[1][r] = e1 * inv;
            }
#pragma unroll
            for (int nt = 0; nt < 2; ++nt)
#pragma unroll
                for (int r = 0; r < 4; ++r)
                    pl[(qb + g * 4 + r) * QN_S + nt * 16 + cl] = (_Float16)po[nt][r];
            // PV (wave-local p rows; compiler orders ds_write->ds_read)
            h8 ap = *(const h8*)(&pl[(qb + cl) * QN_S + g * 8]);
            f4 ov[2];
            ov[0] = 0.0f; ov[1] = 0.0f;
#pragma unroll
            for (int nt = 0; nt < 2; ++nt) {
                h8 bv = *(const h8*)(&vT[(nt * 16 + cl) * VT_S + wm * 32 + g * 8]);
                ov[nt] = __builtin_amdgcn_mfma_f32_16x16x32_f16(ap, bv, ov[nt], 0, 0, 0);
            }
#pragma unroll
            for (int nt = 0; nt < 2; ++nt)
#pragma unroll
                for (int r = 0; r < 4; ++r)
                    outS[(qb + g * 4 + r) * XS_S + h * 32 + nt * 16 + cl] = (_Float16)ov[nt][r];
        }
        __syncthreads();   // protects qn/kn/vT for next head, outS before phase C
    }

    // ================= Phase C: output projection =================
    f4 pacc0[6]; f4 pacc1[6];
#pragma unroll
    for (int ni = 0; ni < 6; ++ni) { pacc0[ni] = 0.0f; pacc1[ni] = 0.0f; }
#pragma unroll
    for (int ks = 0; ks < 6; ++ks) {
        h8 a0 = *(const h8*)(&outS[(wm * 32 + cl) * XS_S + ks * 32 + g * 8]);
        h8 a1 = *(const h8*)(&outS[(wm * 32 + 16 + cl) * XS_S + ks * 32 + g * 8]);
#pragma unroll
        for (int ni = 0; ni < 6; ++ni) {
            int nt = wn * 6 + ni;
            h8 b = *(const h8*)(projp + (((nt * 6 + ks) * 64 + lane) << 3));
            pacc0[ni] = __builtin_amdgcn_mfma_f32_16x16x32_f16(a0, b, pacc0[ni], 0, 0, 0);
            pacc1[ni] = __builtin_amdgcn_mfma_f32_16x16x32_f16(a1, b, pacc1[ni], 0, 0, 0);
        }
    }
#pragma unroll
    for (int m = 0; m < 2; ++m) {
        const f4* pm = m ? pacc1 : pacc0;
        int rl0 = wm * 32 + m * 16 + g * 4;
#pragma unroll
        for (int r = 0; r < 4; ++r) {
            int rl = rl0 + r;
            long grow = (long)(w0 + (rl >> 5)) * 64 + S_of(rl & 31);
            float* po_ = out + grow * 192 + wn * 96 + cl;
#pragma unroll
            for (int ni = 0; ni < 6; ++ni)
                po_[ni * 16] = pm[ni][r] + proj_b[wn * 96 + ni * 16 + cl];
        }
    }
}

extern "C" void kernel_launch(void* const* d_in, const int* in_sizes, int n_in,
                              void* d_out, int out_size, void* d_ws, size_t ws_size,
                              hipStream_t stream) {
    const float* x = (const float*)d_in[0];
    const float* qkv_w = (const float*)d_in[1];
    const float* qkv_b = (const float*)d_in[2];
    const float* proj_w = (const float*)d_in[3];
    const float* proj_b = (const float*)d_in[4];
    const float* logit_scale = (const float*)d_in[5];
    const float* rel_bias_table = (const float*)d_in[6];
    const int* rel_pos_index = (const int*)d_in[7];
    float* out = (float*)d_out;

    const int B = in_sizes[0] / (64 * 192);   // number of windows (8192)

    _Float16* qkvp = (_Float16*)d_ws;                 // 6*6*6*64*8   = 110592 f16
    _Float16* projp = qkvp + 6 * 6 * 6 * 64 * 8;      // 12*6*64*8    = 36864 f16
    float* biask = (float*)(projp + 12 * 6 * 64 * 8); // 6*32*32      = 6144 f32

    pack_kernel<<<96, 256, 0, stream>>>(qkv_w, proj_w, rel_bias_table, rel_pos_index,
                                        qkvp, projp, biask);
    cwa_kernel<<<B / 2, 256, 0, stream>>>(x, qkvp, projp, biask, qkv_b, proj_b,
                                          logit_scale, out);
}